// Round 3
// baseline (354.885 us; speedup 1.0000x reference)
//
#include <hip/hip_runtime.h>
#include <hip/hip_bf16.h>

// Problem constants
#define Bsz 8192
#define Isz 1024
#define Hsz 1024
#define Ksz 2048   // I + H (concatenated GEMM K)
#define Nsz 4096   // 4*H  (stacked gates)

// GEMM tiling (m97 structure)
#define BM 128
#define BN 128
#define BK 32

typedef __attribute__((ext_vector_type(8))) short bf16x8;  // 8 bf16 = 4 VGPRs
typedef __attribute__((ext_vector_type(4))) float f32x4;
typedef __attribute__((ext_vector_type(8))) unsigned short ushort8;

__device__ __forceinline__ void async_copy16(const void* g, void* l) {
  __builtin_amdgcn_global_load_lds(
      (const __attribute__((address_space(1))) void*)g,
      (__attribute__((address_space(3))) void*)l, 16, 0, 0);
}

__device__ __forceinline__ float sigmoid_f(float x) {
  return 1.0f / (1.0f + __expf(-x));
}
__device__ __forceinline__ float tanh_f(float x) {
  x = fminf(15.0f, fmaxf(-15.0f, x));   // avoid inf/inf -> NaN
  const float e = __expf(-2.0f * x);
  return (1.0f - e) / (1.0f + e);
}

// register-only f32 -> bf16 bits (no local-array puns -> no scratch)
__device__ __forceinline__ unsigned short bfc(float f) {
  return __builtin_bit_cast(unsigned short, __float2bfloat16(f));
}
__device__ __forceinline__ ushort8 cvt8v(float4 v0, float4 v1) {
  ushort8 o;
  o[0] = bfc(v0.x); o[1] = bfc(v0.y); o[2] = bfc(v0.z); o[3] = bfc(v0.w);
  o[4] = bfc(v1.x); o[5] = bfc(v1.y); o[6] = bfc(v1.z); o[7] = bfc(v1.w);
  return o;
}

// ---------------------------------------------------------------------------
// Prep: build bf16 A=[x|h] (8192x2048), gate-interleaved bf16 W' (4096x2048)
// with W'[4*hh+g][k] = (k<I ? Wx : Wh)[g*H+hh][k'], and bsum[4*hh+g]=bx+bh.
// 8 floats per thread, all-register conversion.
// ---------------------------------------------------------------------------
__global__ __launch_bounds__(256) void prep_kernel(
    const float* __restrict__ x, const float* __restrict__ h,
    const float* __restrict__ Wx, const float* __restrict__ Wh,
    const float* __restrict__ bx, const float* __restrict__ bh,
    __hip_bfloat16* __restrict__ Abf, __hip_bfloat16* __restrict__ Wbf,
    float* __restrict__ bsum) {
  const int idx = blockIdx.x * 256 + threadIdx.x;
  const int ATH = (Bsz * Ksz) / 8;  // 2,097,152 threads for A
  if (idx < ATH) {
    const int b = idx >> 8;            // row (2048 elems = 256 chunks/row)
    const int k = (idx & 255) << 3;    // col
    const float* src = (k < Isz) ? (x + (size_t)b * Isz + k)
                                 : (h + (size_t)b * Hsz + (k - Isz));
    const float4 v0 = ((const float4*)src)[0];
    const float4 v1 = ((const float4*)src)[1];
    *(ushort8*)(Abf + (size_t)b * Ksz + k) = cvt8v(v0, v1);
  } else {
    const int t2 = idx - ATH;          // 1,048,576 threads for W'
    const int r = t2 >> 8;             // permuted row 4*hh+g
    const int k = (t2 & 255) << 3;
    const int hh = r >> 2, g = r & 3;
    const float* src = (k < Isz) ? (Wx + (size_t)(g * Hsz + hh) * Isz + k)
                                 : (Wh + (size_t)(g * Hsz + hh) * Hsz + (k - Isz));
    const float4 v0 = ((const float4*)src)[0];
    const float4 v1 = ((const float4*)src)[1];
    *(ushort8*)(Wbf + (size_t)r * Ksz + k) = cvt8v(v0, v1);
  }
  if (idx < Nsz) {
    const int hh = idx >> 2, g = idx & 3;
    bsum[idx] = bx[g * Hsz + hh] + bh[g * Hsz + hh];
  }
}

// ---------------------------------------------------------------------------
// GEMM (A·W'^T) + fused LSTM epilogue.
// m97 structure: 128x128 block tile, BK=32, global_load_lds width=16,
// 4 waves in 2x2, each wave 4x4 grid of 16x16x32 bf16 MFMA.
// C/D layout: col = lane&15, row = (lane>>4)*4 + reg.
//
// LDS XOR swizzle (bank-conflict fix): slot (row, j) of As/Bs holds k-qword
// k8 = j ^ phi(row), phi(row) = (row>>1)&3. DMA lane c targets slot c, so it
// loads k8 = (c&3) ^ ((c>>3)&3). Fragment read for (row, q) uses slot
// j = q ^ phi(row); with row = 16*m + cl, phi = (cl>>1)&3. Spreads the
// ds_read_b128 bases over 8 bank-groups -> 2-way (free) vs 8-way before.
// ---------------------------------------------------------------------------
__global__ __launch_bounds__(256) void lstm_gemm_kernel(
    const __hip_bfloat16* __restrict__ A,   // [8192][2048]
    const __hip_bfloat16* __restrict__ W,   // [4096][2048] gate-interleaved
    const float* __restrict__ bsum,         // [4096] gate-interleaved
    const float* __restrict__ c_prev,       // [8192][1024]
    float* __restrict__ c_out,              // [8192][1024]
    float* __restrict__ h_out) {            // [8192][1024]
  __shared__ __hip_bfloat16 As[BM * BK];  // 8 KB
  __shared__ __hip_bfloat16 Bs[BN * BK];  // 8 KB
  __shared__ float Ew[4][16 * 68];        // 17 KB epilogue exchange, per-wave

  const int tid = threadIdx.x;
  const int lane = tid & 63;
  const int wave = tid >> 6;
  const int wm = wave & 1;
  const int wn = wave >> 1;
  const int row0 = blockIdx.x * BM;
  const int col0 = blockIdx.y * BN;

  const __hip_bfloat16* Ag = A + (size_t)row0 * Ksz;
  const __hip_bfloat16* Wg = W + (size_t)col0 * Ksz;

  // staging with XOR swizzle: lane c -> slot c = (row=c>>2, j=c&3),
  // must load k-qword (c&3) ^ ((c>>3)&3) of that row.
  const int c0 = tid, c1 = tid + 256;
  const int ar0 = c0 >> 2, ak0 = ((c0 & 3) ^ ((c0 >> 3) & 3)) * 8;
  const int ar1 = c1 >> 2, ak1 = ((c1 & 3) ^ ((c1 >> 3) & 3)) * 8;

  f32x4 acc[4][4] = {};

  const int q = lane >> 4;    // quad
  const int cl = lane & 15;   // col within 16-wide tile
  const int jsw = (q ^ ((cl >> 1) & 3)) * 8;  // swizzled k-offset for reads

  for (int kt = 0; kt < Ksz; kt += BK) {
    __syncthreads();  // prior iteration's ds_reads complete before overwrite
    async_copy16(Ag + (size_t)ar0 * Ksz + kt + ak0, (char*)As + c0 * 16);
    async_copy16(Ag + (size_t)ar1 * Ksz + kt + ak1, (char*)As + c1 * 16);
    async_copy16(Wg + (size_t)ar0 * Ksz + kt + ak0, (char*)Bs + c0 * 16);
    async_copy16(Wg + (size_t)ar1 * Ksz + kt + ak1, (char*)Bs + c1 * 16);
    __syncthreads();  // vmcnt(0) drain before s_barrier covers the DMA

    bf16x8 af[4], bfr[4];
#pragma unroll
    for (int i = 0; i < 4; i++)
      af[i] = *(const bf16x8*)(As + (wm * 64 + i * 16 + cl) * BK + jsw);
#pragma unroll
    for (int j = 0; j < 4; j++)
      bfr[j] = *(const bf16x8*)(Bs + (wn * 64 + j * 16 + cl) * BK + jsw);
#pragma unroll
    for (int i = 0; i < 4; i++)
#pragma unroll
      for (int j = 0; j < 4; j++)
        acc[i][j] = __builtin_amdgcn_mfma_f32_16x16x32_bf16(af[i], bfr[j],
                                                            acc[i][j], 0, 0, 0);
  }

  // ---- fused LSTM epilogue (LDS round-trip, coalesced I/O) ----
  float bj[4];
#pragma unroll
  for (int j = 0; j < 4; j++)
    bj[j] = bsum[col0 + wn * 64 + j * 16 + cl];

  const int hw = (col0 >> 2) + wn * 16;  // wave's h-window start (16 h values)
  const int r16 = lane >> 2;             // read-phase row 0..15
  const int tt = lane & 3;               // read-phase h-quad 0..3
  float* E = &Ew[wave][0];

#pragma unroll
  for (int i = 0; i < 4; i++) {
    // write phase: lane (q,cl) reg r holds C[q*4+r][j*16+cl] of this 16-row tile
#pragma unroll
    for (int j = 0; j < 4; j++)
#pragma unroll
      for (int r = 0; r < 4; r++)
        E[(q * 4 + r) * 68 + j * 16 + cl] = acc[i][j][r] + bj[j];
    __builtin_amdgcn_wave_barrier();  // keep write->read order (wave-private)
    // read phase: lane owns row r16, h = hw + tt*4 + (0..3); gate cols 4h'+g
    const float* Er = E + r16 * 68 + tt * 16;
    const float4 f0 = ((const float4*)Er)[0];  // gates of h+0
    const float4 f1 = ((const float4*)Er)[1];  // gates of h+1
    const float4 f2 = ((const float4*)Er)[2];  // gates of h+2
    const float4 f3 = ((const float4*)Er)[3];  // gates of h+3

    const int row = row0 + wm * 64 + i * 16 + r16;
    const size_t off = (size_t)row * Hsz + hw + tt * 4;
    const float4 cp4 = *(const float4*)(c_prev + off);
    float4 c4, h4;
    {
      const float cn = sigmoid_f(f0.y) * cp4.x + sigmoid_f(f0.x) * tanh_f(f0.w);
      c4.x = cn; h4.x = sigmoid_f(f0.z) * tanh_f(cn);
    }
    {
      const float cn = sigmoid_f(f1.y) * cp4.y + sigmoid_f(f1.x) * tanh_f(f1.w);
      c4.y = cn; h4.y = sigmoid_f(f1.z) * tanh_f(cn);
    }
    {
      const float cn = sigmoid_f(f2.y) * cp4.z + sigmoid_f(f2.x) * tanh_f(f2.w);
      c4.z = cn; h4.z = sigmoid_f(f2.z) * tanh_f(cn);
    }
    {
      const float cn = sigmoid_f(f3.y) * cp4.w + sigmoid_f(f3.x) * tanh_f(f3.w);
      c4.w = cn; h4.w = sigmoid_f(f3.z) * tanh_f(cn);
    }
    *(float4*)(c_out + off) = c4;
    *(float4*)(h_out + off) = h4;
    __builtin_amdgcn_wave_barrier();  // next i reuses E
  }
}

extern "C" void kernel_launch(void* const* d_in, const int* in_sizes, int n_in,
                              void* d_out, int out_size, void* d_ws,
                              size_t ws_size, hipStream_t stream) {
  (void)in_sizes; (void)n_in; (void)out_size; (void)ws_size;
  const float* x  = (const float*)d_in[0];
  const float* cp = (const float*)d_in[1];
  const float* hp = (const float*)d_in[2];
  const float* Wx = (const float*)d_in[3];
  const float* bx = (const float*)d_in[4];
  const float* Wh = (const float*)d_in[5];
  const float* bh = (const float*)d_in[6];

  __hip_bfloat16* Abf = (__hip_bfloat16*)d_ws;            // 32 MB
  __hip_bfloat16* Wbf = Abf + (size_t)Bsz * Ksz;          // 16 MB
  float* bsum = (float*)(Wbf + (size_t)Nsz * Ksz);        // 16 KB

  float* c_out = (float*)d_out;
  float* h_out = c_out + (size_t)Bsz * Hsz;

  const int total_threads = (Bsz * Ksz) / 8 + (Nsz * Ksz) / 8;  // 3,145,728
  prep_kernel<<<total_threads / 256, 256, 0, stream>>>(x, hp, Wx, Wh, bx, bh,
                                                       Abf, Wbf, bsum);
  dim3 grid(Bsz / BM, Nsz / BN);  // 64 x 32
  lstm_gemm_kernel<<<grid, 256, 0, stream>>>(Abf, Wbf, bsum, cp, c_out, h_out);
}

// Round 4
// 334.197 us; speedup vs baseline: 1.0619x; 1.0619x over previous
//
#include <hip/hip_runtime.h>
#include <hip/hip_bf16.h>

// Problem constants
#define Bsz 8192
#define Isz 1024
#define Hsz 1024
#define Ksz 2048   // I + H (concatenated GEMM K)
#define Nsz 4096   // 4*H  (stacked gates)

// GEMM tiling
#define BM 128
#define BN 128
#define BK 64      // 32 K-iterations; halves barrier-drain count vs BK=32

typedef __attribute__((ext_vector_type(8))) short bf16x8;  // 8 bf16 = 4 VGPRs
typedef __attribute__((ext_vector_type(4))) float f32x4;
typedef __attribute__((ext_vector_type(8))) unsigned short ushort8;

__device__ __forceinline__ void async_copy16(const void* g, void* l) {
  __builtin_amdgcn_global_load_lds(
      (const __attribute__((address_space(1))) void*)g,
      (__attribute__((address_space(3))) void*)l, 16, 0, 0);
}

__device__ __forceinline__ float sigmoid_f(float x) {
  return 1.0f / (1.0f + __expf(-x));
}
__device__ __forceinline__ float tanh_f(float x) {
  x = fminf(15.0f, fmaxf(-15.0f, x));   // avoid inf/inf -> NaN
  const float e = __expf(-2.0f * x);
  return (1.0f - e) / (1.0f + e);
}

// register-only f32 -> bf16 bits (no local-array puns -> no scratch)
__device__ __forceinline__ unsigned short bfc(float f) {
  return __builtin_bit_cast(unsigned short, __float2bfloat16(f));
}
__device__ __forceinline__ ushort8 cvt8v(float4 v0, float4 v1) {
  ushort8 o;
  o[0] = bfc(v0.x); o[1] = bfc(v0.y); o[2] = bfc(v0.z); o[3] = bfc(v0.w);
  o[4] = bfc(v1.x); o[5] = bfc(v1.y); o[6] = bfc(v1.z); o[7] = bfc(v1.w);
  return o;
}

// ---------------------------------------------------------------------------
// Prep: build bf16 A=[x|h] (8192x2048), gate-interleaved bf16 W' (4096x2048)
// with W'[4*hh+g][k] = (k<I ? Wx : Wh)[g*H+hh][k'], and bsum[4*hh+g]=bx+bh.
// ---------------------------------------------------------------------------
__global__ __launch_bounds__(256) void prep_kernel(
    const float* __restrict__ x, const float* __restrict__ h,
    const float* __restrict__ Wx, const float* __restrict__ Wh,
    const float* __restrict__ bx, const float* __restrict__ bh,
    __hip_bfloat16* __restrict__ Abf, __hip_bfloat16* __restrict__ Wbf,
    float* __restrict__ bsum) {
  const int idx = blockIdx.x * 256 + threadIdx.x;
  const int ATH = (Bsz * Ksz) / 8;  // 2,097,152 threads for A
  if (idx < ATH) {
    const int b = idx >> 8;            // row (2048 elems = 256 chunks/row)
    const int k = (idx & 255) << 3;    // col
    const float* src = (k < Isz) ? (x + (size_t)b * Isz + k)
                                 : (h + (size_t)b * Hsz + (k - Isz));
    const float4 v0 = ((const float4*)src)[0];
    const float4 v1 = ((const float4*)src)[1];
    *(ushort8*)(Abf + (size_t)b * Ksz + k) = cvt8v(v0, v1);
  } else {
    const int t2 = idx - ATH;          // 1,048,576 threads for W'
    const int r = t2 >> 8;             // permuted row 4*hh+g
    const int k = (t2 & 255) << 3;
    const int hh = r >> 2, g = r & 3;
    const float* src = (k < Isz) ? (Wx + (size_t)(g * Hsz + hh) * Isz + k)
                                 : (Wh + (size_t)(g * Hsz + hh) * Hsz + (k - Isz));
    const float4 v0 = ((const float4*)src)[0];
    const float4 v1 = ((const float4*)src)[1];
    *(ushort8*)(Wbf + (size_t)r * Ksz + k) = cvt8v(v0, v1);
  }
  if (idx < Nsz) {
    const int hh = idx >> 2, g = idx & 3;
    bsum[idx] = bx[g * Hsz + hh] + bh[g * Hsz + hh];
  }
}

// ---------------------------------------------------------------------------
// GEMM (A·W'^T) + fused LSTM epilogue.
// 128x128 tile, BK=64 (32 barrier pairs), global_load_lds width=16,
// 4 waves 2x2, each wave 4x4 of 16x16x32 bf16 MFMA per K=32 half.
//
// LDS XOR swizzle: row stride = 128 B = 8 qwords; bank-group of a qword slot
// s is s (row drops out mod 32 banks). Store k-qword j of row r at slot
// j ^ (r & 7). DMA chunk c -> slot (row=c>>3, s=c&7) loads qword
// (c&7)^((c>>3)&7). Fragment (row, ks, q) reads slot (ks*4+q)^(cl&7):
// 16 lanes/quad cover all 8 bank-groups twice -> 2-way (free).
//
// LDS union: epilogue exchange E (17,408 B) overlaps As/Bs (32,768 B), dead
// after the K-loop. Total LDS = 32 KB exactly -> 5 blocks/CU.
// ---------------------------------------------------------------------------
__global__ __launch_bounds__(256) void lstm_gemm_kernel(
    const __hip_bfloat16* __restrict__ A,   // [8192][2048]
    const __hip_bfloat16* __restrict__ W,   // [4096][2048] gate-interleaved
    const float* __restrict__ bsum,         // [4096] gate-interleaved
    const float* __restrict__ c_prev,       // [8192][1024]
    float* __restrict__ c_out,              // [8192][1024]
    float* __restrict__ h_out) {            // [8192][1024]
  __shared__ ulong2 smem_raw[2048];         // 32 KB, 16B-aligned
  __hip_bfloat16* As = (__hip_bfloat16*)smem_raw;
  __hip_bfloat16* Bs = As + BM * BK;        // +16 KB

  const int tid = threadIdx.x;
  const int lane = tid & 63;
  const int wave = tid >> 6;
  const int wm = wave & 1;
  const int wn = wave >> 1;
  const int row0 = blockIdx.x * BM;
  const int col0 = blockIdx.y * BN;

  const __hip_bfloat16* Ag = A + (size_t)row0 * Ksz;
  const __hip_bfloat16* Wg = W + (size_t)col0 * Ksz;

  // staging: 1024 chunks of 16 B per matrix; thread stages chunks tid+256p
  int srow[4], sofs[4];
#pragma unroll
  for (int p = 0; p < 4; p++) {
    const int c = tid + p * 256;
    srow[p] = c >> 3;
    sofs[p] = ((c & 7) ^ ((c >> 3) & 7)) << 3;  // swizzled element offset
  }

  f32x4 acc[4][4] = {};

  const int q = lane >> 4;    // quad
  const int cl = lane & 15;   // col within 16-wide tile
  const int phi = cl & 7;     // read-side swizzle phase

  for (int kt = 0; kt < Ksz; kt += BK) {
    __syncthreads();  // prior iteration's ds_reads complete before overwrite
#pragma unroll
    for (int p = 0; p < 4; p++)
      async_copy16(Ag + (size_t)srow[p] * Ksz + kt + sofs[p],
                   (char*)As + (tid + p * 256) * 16);
#pragma unroll
    for (int p = 0; p < 4; p++)
      async_copy16(Wg + (size_t)srow[p] * Ksz + kt + sofs[p],
                   (char*)Bs + (tid + p * 256) * 16);
    __syncthreads();  // vmcnt(0) drain before s_barrier covers the DMA

#pragma unroll
    for (int ks = 0; ks < 2; ks++) {
      const int jsw = ((ks * 4 + q) ^ phi) << 3;  // element offset in row
      bf16x8 af[4], bfr[4];
#pragma unroll
      for (int i = 0; i < 4; i++)
        af[i] = *(const bf16x8*)(As + (wm * 64 + i * 16 + cl) * BK + jsw);
#pragma unroll
      for (int j = 0; j < 4; j++)
        bfr[j] = *(const bf16x8*)(Bs + (wn * 64 + j * 16 + cl) * BK + jsw);
#pragma unroll
      for (int i = 0; i < 4; i++)
#pragma unroll
        for (int j = 0; j < 4; j++)
          acc[i][j] = __builtin_amdgcn_mfma_f32_16x16x32_bf16(
              af[i], bfr[j], acc[i][j], 0, 0, 0);
    }
  }

  // ---- fused LSTM epilogue (LDS round-trip in the union space) ----
  __syncthreads();  // As/Bs dead; E overlaps them
  float* E = (float*)smem_raw + wave * (16 * 68);

  float bj[4];
#pragma unroll
  for (int j = 0; j < 4; j++)
    bj[j] = bsum[col0 + wn * 64 + j * 16 + cl];

  const int hw = (col0 >> 2) + wn * 16;  // wave's h-window start (16 h values)
  const int r16 = lane >> 2;             // read-phase row 0..15
  const int tt = lane & 3;               // read-phase h-quad 0..3

#pragma unroll
  for (int i = 0; i < 4; i++) {
    // write phase: lane (q,cl) reg r holds C[q*4+r][j*16+cl] of this 16-row tile
#pragma unroll
    for (int j = 0; j < 4; j++)
#pragma unroll
      for (int r = 0; r < 4; r++)
        E[(q * 4 + r) * 68 + j * 16 + cl] = acc[i][j][r] + bj[j];
    __builtin_amdgcn_wave_barrier();  // keep write->read order (wave-private)
    // read phase: lane owns row r16, h = hw + tt*4 + (0..3); gate cols 4h'+g
    const float* Er = E + r16 * 68 + tt * 16;
    const float4 f0 = ((const float4*)Er)[0];  // gates of h+0
    const float4 f1 = ((const float4*)Er)[1];  // gates of h+1
    const float4 f2 = ((const float4*)Er)[2];  // gates of h+2
    const float4 f3 = ((const float4*)Er)[3];  // gates of h+3

    const int row = row0 + wm * 64 + i * 16 + r16;
    const size_t off = (size_t)row * Hsz + hw + tt * 4;
    const float4 cp4 = *(const float4*)(c_prev + off);
    float4 c4, h4;
    {
      const float cn = sigmoid_f(f0.y) * cp4.x + sigmoid_f(f0.x) * tanh_f(f0.w);
      c4.x = cn; h4.x = sigmoid_f(f0.z) * tanh_f(cn);
    }
    {
      const float cn = sigmoid_f(f1.y) * cp4.y + sigmoid_f(f1.x) * tanh_f(f1.w);
      c4.y = cn; h4.y = sigmoid_f(f1.z) * tanh_f(cn);
    }
    {
      const float cn = sigmoid_f(f2.y) * cp4.z + sigmoid_f(f2.x) * tanh_f(f2.w);
      c4.z = cn; h4.z = sigmoid_f(f2.z) * tanh_f(cn);
    }
    {
      const float cn = sigmoid_f(f3.y) * cp4.w + sigmoid_f(f3.x) * tanh_f(f3.w);
      c4.w = cn; h4.w = sigmoid_f(f3.z) * tanh_f(cn);
    }
    *(float4*)(c_out + off) = c4;
    *(float4*)(h_out + off) = h4;
    __builtin_amdgcn_wave_barrier();  // next i reuses E
  }
}

extern "C" void kernel_launch(void* const* d_in, const int* in_sizes, int n_in,
                              void* d_out, int out_size, void* d_ws,
                              size_t ws_size, hipStream_t stream) {
  (void)in_sizes; (void)n_in; (void)out_size; (void)ws_size;
  const float* x  = (const float*)d_in[0];
  const float* cp = (const float*)d_in[1];
  const float* hp = (const float*)d_in[2];
  const float* Wx = (const float*)d_in[3];
  const float* bx = (const float*)d_in[4];
  const float* Wh = (const float*)d_in[5];
  const float* bh = (const float*)d_in[6];

  __hip_bfloat16* Abf = (__hip_bfloat16*)d_ws;            // 32 MB
  __hip_bfloat16* Wbf = Abf + (size_t)Bsz * Ksz;          // 16 MB
  float* bsum = (float*)(Wbf + (size_t)Nsz * Ksz);        // 16 KB

  float* c_out = (float*)d_out;
  float* h_out = c_out + (size_t)Bsz * Hsz;

  const int total_threads = (Bsz * Ksz) / 8 + (Nsz * Ksz) / 8;  // 3,145,728
  prep_kernel<<<total_threads / 256, 256, 0, stream>>>(x, hp, Wx, Wh, bx, bh,
                                                       Abf, Wbf, bsum);
  dim3 grid(Bsz / BM, Nsz / BN);  // 64 x 32
  lstm_gemm_kernel<<<grid, 256, 0, stream>>>(Abf, Wbf, bsum, cp, c_out, h_out);
}